// Round 1
// baseline (88.547 us; speedup 1.0000x reference)
//
#include <hip/hip_runtime.h>

constexpr int N_   = 512;
constexpr int C_   = 32;
constexpr int RBF_ = 32;

// out[b,n,ch] = sum_k R[b,n,k,ch] * (Y[b,n,k,:] . tensor[b,k,ch,:])
// R = b2 + W2*relu(b1 + W1*rbf), masked where |rij| < 1e-8.
__global__ __launch_bounds__(256, 4)
void filter_kernel(const float* __restrict__ tensor,  // [B,N,C,3]
                   const float* __restrict__ rbf,     // [B,N,N,RBF]
                   const float* __restrict__ rij,     // [B,N,N,3]
                   const float* __restrict__ W1,      // [C,RBF]
                   const float* __restrict__ b1,      // [C]
                   const float* __restrict__ W2,      // [C,C]
                   const float* __restrict__ b2,      // [C]
                   float* __restrict__ out)           // [B,N,C]
{
    const int bn  = blockIdx.x;      // b*N + n
    const int b   = bn >> 9;
    const int tid = threadIdx.x;
    const int m   = tid & 31;        // channel
    const int g   = tid >> 5;        // group 0..7

    __shared__ float rbf_s[32][32];    // 32 staged rbf rows (4 KB)
    __shared__ float hid_s[8][4][32];  // [group][e][m] hidden vectors (4 KB)
    __shared__ float red_s[8][32];     // final reduction (1 KB)

    // Per-thread weight rows (registers): W1[m][:], W2[m][:]
    float w1r[32], w2r[32];
    #pragma unroll
    for (int q = 0; q < 8; ++q) {
        const float4 a = *reinterpret_cast<const float4*>(W1 + m * 32 + q * 4);
        w1r[q*4+0] = a.x; w1r[q*4+1] = a.y; w1r[q*4+2] = a.z; w1r[q*4+3] = a.w;
        const float4 c = *reinterpret_cast<const float4*>(W2 + m * 32 + q * 4);
        w2r[q*4+0] = c.x; w2r[q*4+1] = c.y; w2r[q*4+2] = c.z; w2r[q*4+3] = c.w;
    }
    const float bias1 = b1[m];
    const float bias2 = b2[m];

    const float* rbf_bn = rbf + (size_t)bn * (N_ * RBF_);
    const float* rij_bn = rij + (size_t)bn * (N_ * 3);
    const float* ten_b  = tensor + (size_t)b * (N_ * C_ * 3);

    float acc = 0.f;

    for (int t = 0; t < N_ / 32; ++t) {   // 16 iterations, 32 edges each
        // Stage 32 rbf rows (4 KB), fully coalesced float4.
        {
            const float4 v =
                *reinterpret_cast<const float4*>(rbf_bn + t * (32 * RBF_) + tid * 4);
            *reinterpret_cast<float4*>(&rbf_s[0][0] + tid * 4) = v;
        }
        __syncthreads();

        // Layer 1: group g handles edges k = t*32 + g + 8*e, e=0..3
        #pragma unroll
        for (int e = 0; e < 4; ++e) {
            const int row = g + 8 * e;
            const float4* rp = reinterpret_cast<const float4*>(&rbf_s[row][0]);
            float h = bias1;
            #pragma unroll
            for (int q = 0; q < 8; ++q) {
                const float4 v = rp[q];   // broadcast read (free)
                h += v.x * w1r[q*4+0] + v.y * w1r[q*4+1]
                   + v.z * w1r[q*4+2] + v.w * w1r[q*4+3];
            }
            hid_s[g][e][m] = fmaxf(h, 0.f);
        }
        __syncthreads();

        // Layer 2 + geometric contraction
        #pragma unroll
        for (int e = 0; e < 4; ++e) {
            const int k = t * 32 + g + 8 * e;
            const float4* hp = reinterpret_cast<const float4*>(&hid_s[g][e][0]);
            float r = bias2;
            #pragma unroll
            for (int q = 0; q < 8; ++q) {
                const float4 v = hp[q];   // broadcast read (free)
                r += v.x * w2r[q*4+0] + v.y * w2r[q*4+1]
                   + v.z * w2r[q*4+2] + v.w * w2r[q*4+3];
            }
            const float rx = rij_bn[k * 3 + 0];
            const float ry = rij_bn[k * 3 + 1];
            const float rz = rij_bn[k * 3 + 2];
            const float r2 = rx * rx + ry * ry + rz * rz;
            const float inv = rsqrtf(fmaxf(r2, 1e-8f));
            const float* tp = ten_b + ((size_t)k * C_ + m) * 3;
            const float s = (rx * tp[0] + ry * tp[1] + rz * tp[2]) * inv;
            const bool valid = sqrtf(r2) >= 1e-8f;   // mask degenerate edges
            acc += valid ? r * s : 0.f;
        }
        __syncthreads();   // hid_s/rbf_s safe to overwrite next iter
    }

    // Reduce partial sums across the 8 groups.
    red_s[g][m] = acc;
    __syncthreads();
    if (tid < 32) {
        float total = 0.f;
        #pragma unroll
        for (int gg = 0; gg < 8; ++gg) total += red_s[gg][tid];
        out[bn * C_ + tid] = total;
    }
}

extern "C" void kernel_launch(void* const* d_in, const int* in_sizes, int n_in,
                              void* d_out, int out_size, void* d_ws, size_t ws_size,
                              hipStream_t stream) {
    const float* tensor = (const float*)d_in[0];
    const float* rbf    = (const float*)d_in[1];
    const float* rij    = (const float*)d_in[2];
    const float* W1     = (const float*)d_in[3];
    const float* b1     = (const float*)d_in[4];
    const float* W2     = (const float*)d_in[5];
    const float* b2     = (const float*)d_in[6];
    float* out = (float*)d_out;

    const int B = 2;
    dim3 grid(B * N_), block(256);
    filter_kernel<<<grid, block, 0, stream>>>(tensor, rbf, rij, W1, b1, W2, b2, out);
}

// Round 2
// 36.349 us; speedup vs baseline: 2.4360x; 2.4360x over previous
//
#include <hip/hip_runtime.h>

using bf16x8 = __attribute__((ext_vector_type(8))) short;
using f32x4  = __attribute__((ext_vector_type(4))) float;

constexpr int N_ = 512;
constexpr int C_ = 32;

// f32 -> bf16 (RNE) bit pattern
__device__ __forceinline__ short f2bf(float x) {
    unsigned u = __builtin_bit_cast(unsigned, x);
    unsigned r = (u + 0x7FFFu + ((u >> 16) & 1u)) >> 16;
    return (short)r;
}

// out[b,n,m] = sum_k mask_k * (b2[m] + W2*relu(b1 + W1*rbf[bn,k,:]))[m] * (rhat_k . tensor[b,k,m,:])
__global__ __launch_bounds__(256, 4)
void filter_mfma(const float* __restrict__ tensor,  // [B,N,C,3]
                 const float* __restrict__ rbf,     // [B,N,N,32]
                 const float* __restrict__ rij,     // [B,N,N,3]
                 const float* __restrict__ W1,      // [32,32]
                 const float* __restrict__ b1,
                 const float* __restrict__ W2,      // [32,32]
                 const float* __restrict__ b2,
                 float* __restrict__ out)           // [B,N,C]
{
    const int bn   = blockIdx.x;
    const int b    = bn >> 9;
    const int tid  = threadIdx.x;
    const int lane = tid & 63;
    const int w    = tid >> 6;   // wave 0..3
    const int lr   = lane & 15;  // row-in-tile (A) / col (B,C/D)
    const int lg   = lane >> 4;  // k-group 0..3

    // Per-wave private H scratch (double-buffered), padded stride 36 f32.
    __shared__ float Hs[4][2][16][36];
    __shared__ float red[4][4][32];

    // B-fragments (W1^T, W2^T as MFMA B-operand): lane holds col m=lr+16nt,
    // k = 8*lg + e  ->  W[m][8*lg+e], contiguous in the weight row.
    bf16x8 B1[2], B2[2];
    float b1v[2], b2v[2];
    #pragma unroll
    for (int nt = 0; nt < 2; ++nt) {
        const float* w1p = W1 + (lr + 16 * nt) * 32 + 8 * lg;
        const float* w2p = W2 + (lr + 16 * nt) * 32 + 8 * lg;
        #pragma unroll
        for (int e = 0; e < 8; ++e) {
            B1[nt][e] = f2bf(w1p[e]);
            B2[nt][e] = f2bf(w2p[e]);
        }
        b1v[nt] = b1[lr + 16 * nt];
        b2v[nt] = b2[lr + 16 * nt];
    }

    const float* rbf_bn = rbf + (size_t)bn * (N_ * 32);
    const float* rij_bn = rij + (size_t)bn * (N_ * 3);
    const float* ten_b  = tensor + (size_t)b * (N_ * C_ * 3);

    float acc0 = 0.f, acc1 = 0.f;

    // Wave w owns edges [w*128, (w+1)*128), 8 tiles of 16 edges.
    for (int j = 0; j < 8; ++j) {
        const int e0  = (w * 8 + j) * 16;
        const int buf = j & 1;

        // A1 fragment: rbf[e0+lr][8*lg .. 8*lg+7]
        const float* ap = rbf_bn + (size_t)(e0 + lr) * 32 + 8 * lg;
        const f32x4 a0 = *reinterpret_cast<const f32x4*>(ap);
        const f32x4 a1 = *reinterpret_cast<const f32x4*>(ap + 4);
        bf16x8 A1;
        #pragma unroll
        for (int e = 0; e < 4; ++e) { A1[e] = f2bf(a0[e]); A1[4 + e] = f2bf(a1[e]); }

        // Layer 1: H = relu(rbf . W1^T + b1), 16 edges x 32 channels
        f32x4 h0 = {0.f, 0.f, 0.f, 0.f}, h1 = {0.f, 0.f, 0.f, 0.f};
        h0 = __builtin_amdgcn_mfma_f32_16x16x32_bf16(A1, B1[0], h0, 0, 0, 0);
        h1 = __builtin_amdgcn_mfma_f32_16x16x32_bf16(A1, B1[1], h1, 0, 0, 0);

        // C-layout -> LDS: row i = 4*lg+r, col m = lr (+16)
        #pragma unroll
        for (int r = 0; r < 4; ++r) {
            Hs[w][buf][4 * lg + r][lr]      = fmaxf(h0[r] + b1v[0], 0.f);
            Hs[w][buf][4 * lg + r][lr + 16] = fmaxf(h1[r] + b1v[1], 0.f);
        }
        // Cross-lane RAW within the wave: drain LDS writes, pin the reads below.
        asm volatile("s_waitcnt lgkmcnt(0)" ::: "memory");
        __builtin_amdgcn_sched_barrier(0);

        // A2 fragment: H[lr][8*lg .. +7] (f32 -> bf16)
        const f32x4 q0 = *reinterpret_cast<const f32x4*>(&Hs[w][buf][lr][8 * lg]);
        const f32x4 q1 = *reinterpret_cast<const f32x4*>(&Hs[w][buf][lr][8 * lg + 4]);
        bf16x8 A2;
        #pragma unroll
        for (int e = 0; e < 4; ++e) { A2[e] = f2bf(q0[e]); A2[4 + e] = f2bf(q1[e]); }

        // Layer 2: R = H . W2^T   (b2 added in epilogue, post-mask)
        f32x4 r0 = {0.f, 0.f, 0.f, 0.f}, r1 = {0.f, 0.f, 0.f, 0.f};
        r0 = __builtin_amdgcn_mfma_f32_16x16x32_bf16(A2, B2[0], r0, 0, 0, 0);
        r1 = __builtin_amdgcn_mfma_f32_16x16x32_bf16(A2, B2[1], r1, 0, 0, 0);

        // Epilogue: lane holds R[e0+4*lg+r][lr(+16)]
        #pragma unroll
        for (int r = 0; r < 4; ++r) {
            const int k = e0 + 4 * lg + r;
            const float rx = rij_bn[k * 3 + 0];
            const float ry = rij_bn[k * 3 + 1];
            const float rz = rij_bn[k * 3 + 2];
            const float r2 = rx * rx + ry * ry + rz * rz;
            const float inv = rsqrtf(fmaxf(r2, 1e-8f));
            const bool valid = (r2 >= 1e-16f);   // sqrt(r2) >= 1e-8
            const float* t0 = ten_b + ((size_t)k * C_ + lr) * 3;
            const float s0 = (rx * t0[0] + ry * t0[1] + rz * t0[2]) * inv;
            const float* t1 = t0 + 48;           // +16 channels * 3
            const float s1 = (rx * t1[0] + ry * t1[1] + rz * t1[2]) * inv;
            acc0 += valid ? (r0[r] + b2v[0]) * s0 : 0.f;
            acc1 += valid ? (r1[r] + b2v[1]) * s1 : 0.f;
        }
    }

    // Reduce partials: lane's cols are m = lr (+16); sum over lg groups & waves.
    red[w][lg][lr]      = acc0;
    red[w][lg][lr + 16] = acc1;
    __syncthreads();
    if (tid < 32) {
        float t = 0.f;
        #pragma unroll
        for (int ww = 0; ww < 4; ++ww)
            #pragma unroll
            for (int g = 0; g < 4; ++g) t += red[ww][g][tid];
        out[bn * C_ + tid] = t;
    }
}

extern "C" void kernel_launch(void* const* d_in, const int* in_sizes, int n_in,
                              void* d_out, int out_size, void* d_ws, size_t ws_size,
                              hipStream_t stream) {
    const float* tensor = (const float*)d_in[0];
    const float* rbf    = (const float*)d_in[1];
    const float* rij    = (const float*)d_in[2];
    const float* W1     = (const float*)d_in[3];
    const float* b1     = (const float*)d_in[4];
    const float* W2     = (const float*)d_in[5];
    const float* b2     = (const float*)d_in[6];
    float* out = (float*)d_out;

    dim3 grid(2 * N_), block(256);
    filter_mfma<<<grid, block, 0, stream>>>(tensor, rbf, rij, W1, b1, W2, b2, out);
}